// Round 15
// baseline (142.120 us; speedup 1.0000x reference)
//
#include <hip/hip_runtime.h>
#include <math.h>

#define Bn 16
#define Nn 256
#define Mm (Nn*(Nn-1)/2)   /* 32640 */
#define CHUNK 4080         /* Mm / 8 */

typedef __attribute__((ext_vector_type(8))) _Float16 f16x8;
typedef __attribute__((ext_vector_type(4))) _Float16 f16x4;
typedef __attribute__((ext_vector_type(4))) float f32x4;

typedef union { f16x8 v; _Float16 h[8]; unsigned u[4]; } H8;
typedef union { f16x4 v; _Float16 h[4]; } H4;

#define MFMA(acc, a, b) \
  acc = __builtin_amdgcn_mfma_f32_16x16x32_f16((a), (b), (acc), 0, 0, 0)

__device__ __forceinline__ void top2_update(float v, int m,
    float& v1, int& i1, float& v2, int& i2)
{
  bool c1 = (v > v1) || (v == v1 && m < i1);
  bool c2 = (v > v2) || (v == v2 && m < i2);
  float nv2 = c1 ? v1 : (c2 ? v : v2);
  int   ni2 = c1 ? i1 : (c2 ? m : i2);
  v1 = c1 ? v : v1;  i1 = c1 ? m : i1;
  v2 = nv2;          i2 = ni2;
}

// ---------------------------------------------------------------------------
// Fused prep (128 blocks): blocks 0..63 transpose W1 -> wtg fp16 [h][k];
// blocks 64..127: obg = fp16(O); A = O@W1a + b1 (f32); C = O@W1b (fp16).
// ---------------------------------------------------------------------------
__global__ __launch_bounds__(256) void prep_all(
    const float* __restrict__ O, const float* __restrict__ W1,
    const float* __restrict__ b1,
    _Float16* __restrict__ wtg, _Float16* __restrict__ obg,
    float* __restrict__ Ag, _Float16* __restrict__ Cgh)
{
  const int t = threadIdx.x;
  if (blockIdx.x < 64) {
    const int h = blockIdx.x;
    wtg[h * 256 + t] = (_Float16)W1[t * 64 + h];
    return;
  }

  __shared__ __align__(16) _Float16 s_ob[64][72];
  __shared__ __align__(16) _Float16 s_w[64][136];   // W1a/b^T [h][k<128]
  const int l = t & 63, wv = t >> 6;
  const int lo = l & 15, g = l >> 4;
  const int bb = blockIdx.x - 64;
  const int b = bb >> 2, rt = bb & 3;
  const int r0 = rt * 64;
  const float* Ob = O + ((size_t)b * Nn + r0) * 64;

  #pragma unroll
  for (int p = 0; p < 4; ++p) {
    int v = t + p * 256;
    int r = v >> 4, c4 = (v & 15) * 4;
    float4 x = ((const float4*)Ob)[v];
    H4 pk; pk.h[0] = (_Float16)x.x; pk.h[1] = (_Float16)x.y;
           pk.h[2] = (_Float16)x.z; pk.h[3] = (_Float16)x.w;
    *(f16x4*)&s_ob[r][c4] = pk.v;
    *(f16x4*)&obg[((size_t)b * Nn + r0 + r) * 64 + c4] = pk.v;
  }
  #pragma unroll
  for (int p = 0; p < 32; ++p) {
    int kk = p * 4 + (t >> 6), h = t & 63;
    s_w[h][kk] = (_Float16)W1[kk * 64 + h];
  }
  __syncthreads();

  H8 aop[2];
  #pragma unroll
  for (int ks = 0; ks < 2; ++ks)
    aop[ks].v = *(const f16x8*)&s_ob[wv * 16 + lo][ks * 32 + g * 8];

  #pragma unroll
  for (int half = 0; half < 2; ++half) {
    #pragma unroll
    for (int nf = 0; nf < 4; ++nf) {
      f32x4 ac = {0.f, 0.f, 0.f, 0.f};
      #pragma unroll
      for (int ks = 0; ks < 2; ++ks) {
        H8 bop; bop.v = *(const f16x8*)&s_w[nf * 16 + lo][half * 64 + ks * 32 + g * 8];
        MFMA(ac, aop[ks].v, bop.v);
      }
      const int h = nf * 16 + lo;
      if (half == 0) {
        float bbv = b1[h];
        #pragma unroll
        for (int r = 0; r < 4; ++r)
          Ag[((size_t)b * Nn + r0 + wv * 16 + g * 4 + r) * 64 + h] = ac[r] + bbv;
      } else {
        #pragma unroll
        for (int r = 0; r < 4; ++r)
          Cgh[((size_t)b * Nn + r0 + wv * 16 + g * 4 + r) * 64 + h] = (_Float16)ac[r];
      }
    }
  }
}

// ---------------------------------------------------------------------------
// Pair kernel (<=128 total regs for 4 waves/SIMD): one block = (batch,
// 16x32 tile), 4 waves. Single acc bank; A-term folded into acc init via
// broadcast ds_read from s_A; W frags read per STEP from s_wt (pitch 144:
// 2-way bank aliasing = free); per-iter epilogue reduces to a per-lane
// partial part[it] (no shfl in the chain); all shfls/stores/top2 deferred
// to a final phase where their latencies overlap.
// Tripwire: WRITE_SIZE >> 2 MB = cap-forced spill (r6/r14).
// ---------------------------------------------------------------------------
__global__ __launch_bounds__(256, 4) void pair_kernel(
    const _Float16* __restrict__ obg,
    const float* __restrict__ Ag,
    const _Float16* __restrict__ Cgh,
    const float* __restrict__ W2,
    const float* __restrict__ b2,
    const _Float16* __restrict__ wtg,
    float* __restrict__ Q,
    float* __restrict__ cand)
{
  __shared__ __align__(16) _Float16 s_wt[64][144];  // pairwise W^T, 288B rows
  __shared__ __align__(16) float s_A[16][68];       // A rows (+b1), f32
  __shared__ float s_w2[64];
  __shared__ float s_red[4][4];

  const int t  = threadIdx.x;
  const int l  = t & 63, wv = t >> 6;
  const int lo = l & 15, g = l >> 4;

  const int blk    = blockIdx.x;
  const int within = blk >> 3;                    // 0..143
  const int batch  = (blk & 7) * 2 + within / 72; // XCD (blk%8) -> batches 2x,2x+1
  int tl           = within % 72;
  int a = 0;
  while (tl >= 8 - (a >> 1)) { tl -= 8 - (a >> 1); ++a; }
  const int c   = (a >> 1) + tl;
  const int ti0 = a * 16, tj0 = c * 32;
  const bool isdiag = (tj0 < ti0 + 16);

  const size_t obase = (size_t)batch * Nn;
  const size_t qbase = (size_t)batch * Mm;

  // ---- stage s_wt (pairwise W half, pitch 144), s_A, s_w2 ----
  {
    const int h = t >> 2, kq = (t & 3) * 32;
    #pragma unroll
    for (int q = 0; q < 4; ++q)
      *(f16x8*)&s_wt[h][kq + q * 8] =
          *(const f16x8*)&wtg[h * 256 + 128 + kq + q * 8];
  }
  {
    int r = t >> 4, c4 = (t & 15) * 4;
    *(f32x4*)&s_A[r][c4] =
        *(const f32x4*)&Ag[(obase + ti0 + r) * 64 + c4];
    if (t < 64) s_w2[t] = W2[t];
  }
  __syncthreads();

  // ---- slim hoists: oj rows (f16), C-init (f16) ----
  H8 ojb[2][2];
  #pragma unroll
  for (int jh = 0; jh < 2; ++jh) {
    ojb[jh][0].v = *(const f16x8*)&obg[(obase + tj0 + jh * 16 + lo) * 64 + g * 8];
    ojb[jh][1].v = *(const f16x8*)&obg[(obase + tj0 + jh * 16 + lo) * 64 + 32 + g * 8];
  }
  H4 cinb[2][4];
  #pragma unroll
  for (int jh = 0; jh < 2; ++jh)
    #pragma unroll
    for (int nf = 0; nf < 4; ++nf)
      cinb[jh][nf].v = *(const f16x4*)
          &Cgh[(obase + tj0 + jh * 16 + lo) * 64 + nf * 16 + g * 4];

  // ---- main loop: 8 (ii,jh) iterations, per-lane partials only ----
  H8 oib0, oib1;
  float part[8];

  #pragma unroll
  for (int it = 0; it < 8; ++it) {
    const int ii = it >> 1, jh = it & 1;
    const int iL = wv * 4 + ii;

    if (jh == 0) {   // new i-row: oi from global (L2-hot)
      oib0.v = *(const f16x8*)&obg[(obase + ti0 + iL) * 64 + g * 8];
      oib1.v = *(const f16x8*)&obg[(obase + ti0 + iL) * 64 + 32 + g * 8];
    }

    // acc init = A-row terms (broadcast ds_read_b128, conflict-free)
    f32x4 acc[4];
    #pragma unroll
    for (int nf = 0; nf < 4; ++nf)
      acc[nf] = *(const f32x4*)&s_A[iL][nf * 16 + g * 4];

    // feature build (packed fp16, no cvts)
    H8 f0, f1, f2, f3;
    {
      H8 d0, d1;
      d0.v = oib0.v - ojb[jh][0].v;
      d1.v = oib1.v - ojb[jh][1].v;
      #pragma unroll
      for (int q = 0; q < 4; ++q) {
        d0.u[q] &= 0x7FFF7FFFu;
        d1.u[q] &= 0x7FFF7FFFu;
      }
      f0 = d0; f1 = d1;
      f2.v = oib0.v * ojb[jh][0].v;
      f3.v = oib1.v * ojb[jh][1].v;
    }

    // 16 MFMA; W frags streamed from LDS (pitch 144 -> 2-way = free)
    #pragma unroll
    for (int ks = 0; ks < 4; ++ks) {
      H8 w0, w1, w2q, w3;
      w0.v  = *(const f16x8*)&s_wt[      lo][ks * 32 + g * 8];
      w1.v  = *(const f16x8*)&s_wt[16 + lo][ks * 32 + g * 8];
      w2q.v = *(const f16x8*)&s_wt[32 + lo][ks * 32 + g * 8];
      w3.v  = *(const f16x8*)&s_wt[48 + lo][ks * 32 + g * 8];
      const f16x8 fk = (ks == 0) ? f0.v : (ks == 1) ? f1.v
                     : (ks == 2) ? f2.v : f3.v;
      MFMA(acc[0], w0.v,  fk);
      MFMA(acc[1], w1.v,  fk);
      MFMA(acc[2], w2q.v, fk);
      MFMA(acc[3], w3.v,  fk);
    }

    // per-lane partial (relu + W2 from LDS broadcast); NO shfl here
    float p0 = 0.f, p1 = 0.f;
    #pragma unroll
    for (int nf = 0; nf < 4; ++nf) {
      f32x4 w2v = *(const f32x4*)&s_w2[nf * 16 + g * 4];
      #pragma unroll
      for (int r = 0; r < 4; ++r) {
        float z = acc[nf][r] + (float)cinb[jh][nf].h[r];
        if (nf & 1) p1 = fmaf(fmaxf(z, 0.f), w2v[r], p1);
        else        p0 = fmaf(fmaxf(z, 0.f), w2v[r], p0);
      }
    }
    part[it] = p0 + p1;
  }

  // ---- final phase: all shfls (overlapping), stores, top-2 ----
  #pragma unroll
  for (int it = 0; it < 8; ++it) {
    float p = part[it];
    p += __shfl_xor(p, 16);
    p += __shfl_xor(p, 32);
    part[it] = p;
  }

  float v1 = -INFINITY, v2 = -INFINITY;
  int   i1 = 0x7fffffff, i2 = 0x7fffffff;
  const float b2v = b2[0];
  if (l < 16) {
    #pragma unroll
    for (int it = 0; it < 8; ++it) {
      const int ii = it >> 1, jh = it & 1;
      const int i = ti0 + wv * 4 + ii;
      const int j = tj0 + jh * 16 + l;
      if (!isdiag || j > i) {
        const int mb = i * (Nn - 1) - (i * (i - 1)) / 2 - i - 1;
        const float qv = part[it] + b2v;
        Q[qbase + mb + j] = qv;
        top2_update(qv, mb + j, v1, i1, v2, i2);
      }
    }
  }

  #pragma unroll
  for (int s = 1; s < 64; s <<= 1) {
    float u1 = __shfl_xor(v1, s); int j1 = __shfl_xor(i1, s);
    float u2 = __shfl_xor(v2, s); int j2 = __shfl_xor(i2, s);
    top2_update(u1, j1, v1, i1, v2, i2);
    top2_update(u2, j2, v1, i1, v2, i2);
  }
  if (l == 0) {
    s_red[wv][0] = v1; s_red[wv][1] = __int_as_float(i1);
    s_red[wv][2] = v2; s_red[wv][3] = __int_as_float(i2);
  }
  __syncthreads();
  if (t == 0) {
    float a1 = s_red[0][0]; int x1 = __float_as_int(s_red[0][1]);
    float a2 = s_red[0][2]; int x2 = __float_as_int(s_red[0][3]);
    #pragma unroll
    for (int e = 1; e < 4; ++e) {
      top2_update(s_red[e][0], __float_as_int(s_red[e][1]), a1, x1, a2, x2);
      top2_update(s_red[e][2], __float_as_int(s_red[e][3]), a1, x1, a2, x2);
    }
    float* cp = cand + ((size_t)batch * 72 + within % 72) * 4;
    cp[0] = a1; cp[1] = __int_as_float(x1);
    cp[2] = a2; cp[3] = __int_as_float(x2);
  }
}

// ---------------------------------------------------------------------------
// Rank+mask kernel: grid (B x 8). Merges 144 candidates -> top-8,
// recomputes those 8 exactly in fp32 (wave-per-candidate, h-per-lane),
// picks exact top-2 (jax tie rule), writes mask slice.
// ---------------------------------------------------------------------------
__global__ __launch_bounds__(256) void rankmask_kernel(
    const float* __restrict__ O, const float* __restrict__ W1,
    const float* __restrict__ b1, const float* __restrict__ W2,
    const float* __restrict__ cand, float* __restrict__ mask)
{
  const int b   = blockIdx.x >> 3;
  const int cch = blockIdx.x & 7;
  const int t   = threadIdx.x;
  const int wv  = t >> 6, h = t & 63;
  __shared__ float s_cv[144];
  __shared__ int   s_ci[144];
  __shared__ int   s_m[8];
  __shared__ int   s_ij[8][2];
  __shared__ float s_or[8][2][64];
  __shared__ float s_qe[8];
  __shared__ int   s_k0, s_k1;

  if (t < 144) {
    const float* cp = cand + (size_t)(b * 72 + (t >> 1)) * 4;
    s_cv[t] = cp[(t & 1) * 2];
    s_ci[t] = __float_as_int(cp[(t & 1) * 2 + 1]);
  }
  __syncthreads();
  if (t < 144) {
    float v = s_cv[t]; int m = s_ci[t];
    int rank = 0;
    for (int e = 0; e < 144; ++e) {
      float u = s_cv[e]; int n = s_ci[e];
      rank += (u > v || (u == v && n < m)) ? 1 : 0;
    }
    if (rank < 8) s_m[rank] = m;
  }
  __syncthreads();
  if (t < 16) {
    int m = s_m[t >> 1];
    int i = 0, rem = m;
    while (rem >= Nn - 1 - i) { rem -= Nn - 1 - i; ++i; }
    int j = i + 1 + rem;
    s_ij[t >> 1][t & 1] = (t & 1) ? j : i;
  }
  __syncthreads();
  {
    int cc = t >> 5, rr = (t >> 4) & 1, c4 = (t & 15) * 4;
    int row = s_ij[cc][rr];
    *(float4*)&s_or[cc][rr][c4] = *(const float4*)&O[((size_t)b * Nn + row) * 64 + c4];
  }
  __syncthreads();
  #pragma unroll
  for (int p = 0; p < 2; ++p) {
    const int cc = p * 4 + wv;
    float z = b1[h];
    #pragma unroll 8
    for (int d = 0; d < 64; ++d) {
      float oi = s_or[cc][0][d], oj = s_or[cc][1][d];
      float f3 = fabsf(oi - oj), f4 = oi * oj;
      z += oi * W1[d * 64 + h] + oj * W1[(64 + d) * 64 + h]
         + f3 * W1[(128 + d) * 64 + h] + f4 * W1[(192 + d) * 64 + h];
    }
    float part = fmaxf(z, 0.f) * W2[h];
    #pragma unroll
    for (int s = 1; s < 64; s <<= 1) part += __shfl_xor(part, s);
    if (h == 0) s_qe[cc] = part;
  }
  __syncthreads();
  if (t == 0) {
    float v1 = -INFINITY, v2 = -INFINITY;
    int   i1 = 0x7fffffff, i2 = 0x7fffffff;
    for (int e = 0; e < 8; ++e)
      top2_update(s_qe[e], s_m[e], v1, i1, v2, i2);
    s_k0 = i1; s_k1 = i2;
  }
  __syncthreads();

  const int k0 = s_k0, k1 = s_k1;
  float* mb = mask + (size_t)b * Mm;
  const int m0 = cch * CHUNK;
  for (int m = m0 + t; m < m0 + CHUNK; m += 256)
    mb[m] = (m == k0 || m == k1) ? 1.0f : 0.0f;
}

extern "C" void kernel_launch(void* const* d_in, const int* in_sizes, int n_in,
                              void* d_out, int out_size, void* d_ws, size_t ws_size,
                              hipStream_t stream) {
  const float* O  = (const float*)d_in[0];
  const float* W1 = (const float*)d_in[1];
  const float* b1 = (const float*)d_in[2];
  const float* W2 = (const float*)d_in[3];
  const float* b2 = (const float*)d_in[4];

  float* Q    = (float*)d_out;
  float* mask = Q + (size_t)Bn * Mm;

  char* ws = (char*)d_ws;
  _Float16* wtg = (_Float16*)ws;                               // 32768 B
  _Float16* obg = (_Float16*)(ws + 32768);                     // 524288 B
  float*    Ag  = (float*)(ws + 32768 + 524288);               // 1048576 B
  _Float16* Cgh = (_Float16*)(ws + 32768 + 524288 + 1048576);  // 524288 B
  float*    cand = (float*)(ws + 32768 + 524288 + 1048576 + 524288); // 18432 B

  prep_all<<<dim3(128), dim3(256), 0, stream>>>(O, W1, b1, wtg, obg, Ag, Cgh);
  pair_kernel<<<dim3(Bn * 72), dim3(256), 0, stream>>>(obg, Ag, Cgh, W2, b2, wtg, Q, cand);
  rankmask_kernel<<<dim3(Bn * 8), dim3(256), 0, stream>>>(O, W1, b1, W2, cand, mask);
}

// Round 16
// 56.981 us; speedup vs baseline: 2.4941x; 2.4941x over previous
//
#include <hip/hip_runtime.h>
#include <math.h>

#define Bn 16
#define Nn 256
#define Mm (Nn*(Nn-1)/2)   /* 32640 */
#define CHUNK 4080         /* Mm / 8 */

typedef __attribute__((ext_vector_type(8))) _Float16 f16x8;
typedef __attribute__((ext_vector_type(4))) _Float16 f16x4;
typedef __attribute__((ext_vector_type(4))) float f32x4;

typedef union { f16x8 v; _Float16 h[8]; unsigned u[4]; } H8;
typedef union { f16x4 v; _Float16 h[4]; } H4;

#define MFMA(acc, a, b) \
  acc = __builtin_amdgcn_mfma_f32_16x16x32_f16((a), (b), (acc), 0, 0, 0)

__device__ __forceinline__ void top2_update(float v, int m,
    float& v1, int& i1, float& v2, int& i2)
{
  bool c1 = (v > v1) || (v == v1 && m < i1);
  bool c2 = (v > v2) || (v == v2 && m < i2);
  float nv2 = c1 ? v1 : (c2 ? v : v2);
  int   ni2 = c1 ? i1 : (c2 ? m : i2);
  v1 = c1 ? v : v1;  i1 = c1 ? m : i1;
  v2 = nv2;          i2 = ni2;
}

// ---------------------------------------------------------------------------
// Fused prep (128 blocks): blocks 0..63 transpose W1 -> wtg fp16 [h][k];
// blocks 64..127: obg = fp16(O); A = O@W1a + b1 (f32); C = O@W1b (fp16).
// ---------------------------------------------------------------------------
__global__ __launch_bounds__(256) void prep_all(
    const float* __restrict__ O, const float* __restrict__ W1,
    const float* __restrict__ b1,
    _Float16* __restrict__ wtg, _Float16* __restrict__ obg,
    float* __restrict__ Ag, _Float16* __restrict__ Cgh)
{
  const int t = threadIdx.x;
  if (blockIdx.x < 64) {
    const int h = blockIdx.x;
    wtg[h * 256 + t] = (_Float16)W1[t * 64 + h];
    return;
  }

  __shared__ __align__(16) _Float16 s_ob[64][72];
  __shared__ __align__(16) _Float16 s_w[64][136];   // W1a/b^T [h][k<128]
  const int l = t & 63, wv = t >> 6;
  const int lo = l & 15, g = l >> 4;
  const int bb = blockIdx.x - 64;
  const int b = bb >> 2, rt = bb & 3;
  const int r0 = rt * 64;
  const float* Ob = O + ((size_t)b * Nn + r0) * 64;

  #pragma unroll
  for (int p = 0; p < 4; ++p) {
    int v = t + p * 256;
    int r = v >> 4, c4 = (v & 15) * 4;
    float4 x = ((const float4*)Ob)[v];
    H4 pk; pk.h[0] = (_Float16)x.x; pk.h[1] = (_Float16)x.y;
           pk.h[2] = (_Float16)x.z; pk.h[3] = (_Float16)x.w;
    *(f16x4*)&s_ob[r][c4] = pk.v;
    *(f16x4*)&obg[((size_t)b * Nn + r0 + r) * 64 + c4] = pk.v;
  }
  #pragma unroll
  for (int p = 0; p < 32; ++p) {
    int kk = p * 4 + (t >> 6), h = t & 63;
    s_w[h][kk] = (_Float16)W1[kk * 64 + h];
  }
  __syncthreads();

  H8 aop[2];
  #pragma unroll
  for (int ks = 0; ks < 2; ++ks)
    aop[ks].v = *(const f16x8*)&s_ob[wv * 16 + lo][ks * 32 + g * 8];

  #pragma unroll
  for (int half = 0; half < 2; ++half) {
    #pragma unroll
    for (int nf = 0; nf < 4; ++nf) {
      f32x4 ac = {0.f, 0.f, 0.f, 0.f};
      #pragma unroll
      for (int ks = 0; ks < 2; ++ks) {
        H8 bop; bop.v = *(const f16x8*)&s_w[nf * 16 + lo][half * 64 + ks * 32 + g * 8];
        MFMA(ac, aop[ks].v, bop.v);
      }
      const int h = nf * 16 + lo;
      if (half == 0) {
        float bbv = b1[h];
        #pragma unroll
        for (int r = 0; r < 4; ++r)
          Ag[((size_t)b * Nn + r0 + wv * 16 + g * 4 + r) * 64 + h] = ac[r] + bbv;
      } else {
        #pragma unroll
        for (int r = 0; r < 4; ++r)
          Cgh[((size_t)b * Nn + r0 + wv * 16 + g * 4 + r) * 64 + h] = (_Float16)ac[r];
      }
    }
  }
}

// ---------------------------------------------------------------------------
// Pair kernel (r13 pipeline + LDS-sourced steady state): one block =
// (batch, 16x32 tile), 4 waves. bfr register-hoisted (proven best at
// (256,2), VGPR ~100, no spill); oi/A rows staged in LDS so LOADROW is
// broadcast ds_reads (not 200-900cyc global); cin hoisted f32; setprio(1)
// around the MFMA cluster (waves run barrier-free independent phases).
// Tripwire: WRITE_SIZE >> 2 MB = spill (r6/r14/r15).
// ---------------------------------------------------------------------------
__global__ __launch_bounds__(256, 2) void pair_kernel(
    const _Float16* __restrict__ obg,
    const float* __restrict__ Ag,
    const _Float16* __restrict__ Cgh,
    const float* __restrict__ W2,
    const float* __restrict__ b2,
    const _Float16* __restrict__ wtg,
    float* __restrict__ Q,
    float* __restrict__ cand)
{
  __shared__ __align__(16) _Float16 s_wt[64][136];
  __shared__ __align__(16) _Float16 s_oi[16][72];
  __shared__ __align__(16) float s_A[16][68];
  __shared__ float s_w2[64];
  __shared__ float s_red[4][4];

  const int t  = threadIdx.x;
  const int l  = t & 63, wv = t >> 6;
  const int lo = l & 15, g = l >> 4;

  const int blk    = blockIdx.x;
  const int within = blk >> 3;                    // 0..143
  const int batch  = (blk & 7) * 2 + within / 72; // XCD (blk%8) -> batches 2x,2x+1
  int tl           = within % 72;
  int a = 0;
  while (tl >= 8 - (a >> 1)) { tl -= 8 - (a >> 1); ++a; }
  const int c   = (a >> 1) + tl;
  const int ti0 = a * 16, tj0 = c * 32;
  const bool isdiag = (tj0 < ti0 + 16);

  const size_t obase = (size_t)batch * Nn;
  const size_t qbase = (size_t)batch * Mm;

  // ---- stage s_wt (pairwise W half) + s_oi + s_A + s_w2 ----
  {
    const int h = t >> 2, kq = (t & 3) * 32;
    #pragma unroll
    for (int q = 0; q < 4; ++q)
      *(f16x8*)&s_wt[h][kq + q * 8] =
          *(const f16x8*)&wtg[h * 256 + 128 + kq + q * 8];
  }
  {
    int r = t >> 4, c4 = (t & 15) * 4;
    *(f16x4*)&s_oi[r][c4] =
        *(const f16x4*)&obg[(obase + ti0 + r) * 64 + c4];
    *(f32x4*)&s_A[r][c4] =
        *(const f32x4*)&Ag[(obase + ti0 + r) * 64 + c4];
    if (t < 64) s_w2[t] = W2[t];
  }
  __syncthreads();

  // ---- hoists (r13 set): W frags, oj rows, C-init f32 ----
  H8 bfr[4][4];
  #pragma unroll
  for (int ks = 0; ks < 4; ++ks)
    #pragma unroll
    for (int nf = 0; nf < 4; ++nf)
      bfr[ks][nf].v = *(const f16x8*)&s_wt[nf * 16 + lo][ks * 32 + g * 8];

  H8 ojb[2][2];
  #pragma unroll
  for (int jh = 0; jh < 2; ++jh) {
    ojb[jh][0].v = *(const f16x8*)&obg[(obase + tj0 + jh * 16 + lo) * 64 + g * 8];
    ojb[jh][1].v = *(const f16x8*)&obg[(obase + tj0 + jh * 16 + lo) * 64 + 32 + g * 8];
  }
  f32x4 cinf[2][4];
  #pragma unroll
  for (int jh = 0; jh < 2; ++jh)
    #pragma unroll
    for (int nf = 0; nf < 4; ++nf) {
      H4 cx; cx.v = *(const f16x4*)
          &Cgh[(obase + tj0 + jh * 16 + lo) * 64 + nf * 16 + g * 4];
      #pragma unroll
      for (int r = 0; r < 4; ++r) cinf[jh][nf][r] = (float)cx.h[r];
    }

  const float b2v = b2[0];

  // ---- pipeline state (r13) ----
  H8 oib0, oib1;
  f32x4 as4[4];
  int iG = 0, mbG = 0, iP = 0, mbP = 0;
  f32x4 acc0[4], acc1[4];
  H8 f0, f1, f2, f3;
  float v1 = -INFINITY, v2 = -INFINITY;
  int   i1 = 0x7fffffff, i2 = 0x7fffffff;

  auto LOADROW = [&](int ii) {
    const int iL = wv * 4 + ii;
    oib0.v = *(const f16x8*)&s_oi[iL][g * 8];
    oib1.v = *(const f16x8*)&s_oi[iL][32 + g * 8];
    #pragma unroll
    for (int nf = 0; nf < 4; ++nf)
      as4[nf] = *(const f32x4*)&s_A[iL][nf * 16 + g * 4];
    iG = ti0 + iL;
    mbG = iG * (Nn - 1) - (iG * (iG - 1)) / 2 - iG - 1;
  };

  auto BUILD = [&](const H8& oj0, const H8& oj1) {
    H8 d0, d1;
    d0.v = oib0.v - oj0.v;
    d1.v = oib1.v - oj1.v;
    #pragma unroll
    for (int q = 0; q < 4; ++q) {
      d0.u[q] &= 0x7FFF7FFFu;
      d1.u[q] &= 0x7FFF7FFFu;
    }
    f0 = d0; f1 = d1;
    f2.v = oib0.v * oj0.v;
    f3.v = oib1.v * oj1.v;
  };

  auto STEP = [&](f32x4 (&acc)[4]) {
    #pragma unroll
    for (int nf = 0; nf < 4; ++nf) acc[nf] = as4[nf];
    __builtin_amdgcn_s_setprio(1);
    MFMA(acc[0], bfr[0][0].v, f0.v); MFMA(acc[1], bfr[0][1].v, f0.v);
    MFMA(acc[2], bfr[0][2].v, f0.v); MFMA(acc[3], bfr[0][3].v, f0.v);
    MFMA(acc[0], bfr[1][0].v, f1.v); MFMA(acc[1], bfr[1][1].v, f1.v);
    MFMA(acc[2], bfr[1][2].v, f1.v); MFMA(acc[3], bfr[1][3].v, f1.v);
    MFMA(acc[0], bfr[2][0].v, f2.v); MFMA(acc[1], bfr[2][1].v, f2.v);
    MFMA(acc[2], bfr[2][2].v, f2.v); MFMA(acc[3], bfr[2][3].v, f2.v);
    MFMA(acc[0], bfr[3][0].v, f3.v); MFMA(acc[1], bfr[3][1].v, f3.v);
    MFMA(acc[2], bfr[3][2].v, f3.v); MFMA(acc[3], bfr[3][3].v, f3.v);
    __builtin_amdgcn_s_setprio(0);
  };

  auto EPI = [&](f32x4 (&acc)[4], int jhE, int iE, int mbE) {
    float part = 0.f;
    #pragma unroll
    for (int nf = 0; nf < 4; ++nf) {
      f32x4 w2v = *(const f32x4*)&s_w2[nf * 16 + g * 4];
      #pragma unroll
      for (int r = 0; r < 4; ++r) {
        float z = acc[nf][r] + cinf[jhE][nf][r];
        part = fmaf(fmaxf(z, 0.f), w2v[r], part);
      }
    }
    part += __shfl_xor(part, 16);
    part += __shfl_xor(part, 32);
    if (l < 16) {
      const int j = tj0 + jhE * 16 + l;
      if (!isdiag || j > iE) {
        const float qv = part + b2v;
        const int m = mbE + j;
        Q[qbase + m] = qv;
        top2_update(qv, m, v1, i1, v2, i2);
      }
    }
  };

  // ---- hand-scheduled pipeline over 8 (ii,jh) iterations ----
  LOADROW(0);
  BUILD(ojb[0][0], ojb[0][1]); STEP(acc0);
  BUILD(ojb[1][0], ojb[1][1]); STEP(acc1); EPI(acc0, 0, iG, mbG);

  iP = iG; mbP = mbG; LOADROW(1);
  EPI(acc1, 1, iP, mbP);
  BUILD(ojb[0][0], ojb[0][1]); STEP(acc0);
  BUILD(ojb[1][0], ojb[1][1]); STEP(acc1); EPI(acc0, 0, iG, mbG);

  iP = iG; mbP = mbG; LOADROW(2);
  EPI(acc1, 1, iP, mbP);
  BUILD(ojb[0][0], ojb[0][1]); STEP(acc0);
  BUILD(ojb[1][0], ojb[1][1]); STEP(acc1); EPI(acc0, 0, iG, mbG);

  iP = iG; mbP = mbG; LOADROW(3);
  EPI(acc1, 1, iP, mbP);
  BUILD(ojb[0][0], ojb[0][1]); STEP(acc0);
  BUILD(ojb[1][0], ojb[1][1]); STEP(acc1); EPI(acc0, 0, iG, mbG);
  EPI(acc1, 1, iG, mbG);

  // ---- wave + block top-2 reduce -> cand ----
  #pragma unroll
  for (int s = 1; s < 64; s <<= 1) {
    float u1 = __shfl_xor(v1, s); int j1 = __shfl_xor(i1, s);
    float u2 = __shfl_xor(v2, s); int j2 = __shfl_xor(i2, s);
    top2_update(u1, j1, v1, i1, v2, i2);
    top2_update(u2, j2, v1, i1, v2, i2);
  }
  if (l == 0) {
    s_red[wv][0] = v1; s_red[wv][1] = __int_as_float(i1);
    s_red[wv][2] = v2; s_red[wv][3] = __int_as_float(i2);
  }
  __syncthreads();
  if (t == 0) {
    float a1 = s_red[0][0]; int x1 = __float_as_int(s_red[0][1]);
    float a2 = s_red[0][2]; int x2 = __float_as_int(s_red[0][3]);
    #pragma unroll
    for (int e = 1; e < 4; ++e) {
      top2_update(s_red[e][0], __float_as_int(s_red[e][1]), a1, x1, a2, x2);
      top2_update(s_red[e][2], __float_as_int(s_red[e][3]), a1, x1, a2, x2);
    }
    float* cp = cand + ((size_t)batch * 72 + within % 72) * 4;
    cp[0] = a1; cp[1] = __int_as_float(x1);
    cp[2] = a2; cp[3] = __int_as_float(x2);
  }
}

// ---------------------------------------------------------------------------
// Rank+mask kernel: grid (B x 8). Merges 144 candidates -> top-8,
// recomputes those 8 exactly in fp32 (wave-per-candidate, h-per-lane),
// picks exact top-2 (jax tie rule), writes mask slice.
// ---------------------------------------------------------------------------
__global__ __launch_bounds__(256) void rankmask_kernel(
    const float* __restrict__ O, const float* __restrict__ W1,
    const float* __restrict__ b1, const float* __restrict__ W2,
    const float* __restrict__ cand, float* __restrict__ mask)
{
  const int b   = blockIdx.x >> 3;
  const int cch = blockIdx.x & 7;
  const int t   = threadIdx.x;
  const int wv  = t >> 6, h = t & 63;
  __shared__ float s_cv[144];
  __shared__ int   s_ci[144];
  __shared__ int   s_m[8];
  __shared__ int   s_ij[8][2];
  __shared__ float s_or[8][2][64];
  __shared__ float s_qe[8];
  __shared__ int   s_k0, s_k1;

  if (t < 144) {
    const float* cp = cand + (size_t)(b * 72 + (t >> 1)) * 4;
    s_cv[t] = cp[(t & 1) * 2];
    s_ci[t] = __float_as_int(cp[(t & 1) * 2 + 1]);
  }
  __syncthreads();
  if (t < 144) {
    float v = s_cv[t]; int m = s_ci[t];
    int rank = 0;
    for (int e = 0; e < 144; ++e) {
      float u = s_cv[e]; int n = s_ci[e];
      rank += (u > v || (u == v && n < m)) ? 1 : 0;
    }
    if (rank < 8) s_m[rank] = m;
  }
  __syncthreads();
  if (t < 16) {
    int m = s_m[t >> 1];
    int i = 0, rem = m;
    while (rem >= Nn - 1 - i) { rem -= Nn - 1 - i; ++i; }
    int j = i + 1 + rem;
    s_ij[t >> 1][t & 1] = (t & 1) ? j : i;
  }
  __syncthreads();
  {
    int cc = t >> 5, rr = (t >> 4) & 1, c4 = (t & 15) * 4;
    int row = s_ij[cc][rr];
    *(float4*)&s_or[cc][rr][c4] = *(const float4*)&O[((size_t)b * Nn + row) * 64 + c4];
  }
  __syncthreads();
  #pragma unroll
  for (int p = 0; p < 2; ++p) {
    const int cc = p * 4 + wv;
    float z = b1[h];
    #pragma unroll 8
    for (int d = 0; d < 64; ++d) {
      float oi = s_or[cc][0][d], oj = s_or[cc][1][d];
      float f3 = fabsf(oi - oj), f4 = oi * oj;
      z += oi * W1[d * 64 + h] + oj * W1[(64 + d) * 64 + h]
         + f3 * W1[(128 + d) * 64 + h] + f4 * W1[(192 + d) * 64 + h];
    }
    float part = fmaxf(z, 0.f) * W2[h];
    #pragma unroll
    for (int s = 1; s < 64; s <<= 1) part += __shfl_xor(part, s);
    if (h == 0) s_qe[cc] = part;
  }
  __syncthreads();
  if (t == 0) {
    float v1 = -INFINITY, v2 = -INFINITY;
    int   i1 = 0x7fffffff, i2 = 0x7fffffff;
    for (int e = 0; e < 8; ++e)
      top2_update(s_qe[e], s_m[e], v1, i1, v2, i2);
    s_k0 = i1; s_k1 = i2;
  }
  __syncthreads();

  const int k0 = s_k0, k1 = s_k1;
  float* mb = mask + (size_t)b * Mm;
  const int m0 = cch * CHUNK;
  for (int m = m0 + t; m < m0 + CHUNK; m += 256)
    mb[m] = (m == k0 || m == k1) ? 1.0f : 0.0f;
}

extern "C" void kernel_launch(void* const* d_in, const int* in_sizes, int n_in,
                              void* d_out, int out_size, void* d_ws, size_t ws_size,
                              hipStream_t stream) {
  const float* O  = (const float*)d_in[0];
  const float* W1 = (const float*)d_in[1];
  const float* b1 = (const float*)d_in[2];
  const float* W2 = (const float*)d_in[3];
  const float* b2 = (const float*)d_in[4];

  float* Q    = (float*)d_out;
  float* mask = Q + (size_t)Bn * Mm;

  char* ws = (char*)d_ws;
  _Float16* wtg = (_Float16*)ws;                               // 32768 B
  _Float16* obg = (_Float16*)(ws + 32768);                     // 524288 B
  float*    Ag  = (float*)(ws + 32768 + 524288);               // 1048576 B
  _Float16* Cgh = (_Float16*)(ws + 32768 + 524288 + 1048576);  // 524288 B
  float*    cand = (float*)(ws + 32768 + 524288 + 1048576 + 524288); // 18432 B

  prep_all<<<dim3(128), dim3(256), 0, stream>>>(O, W1, b1, wtg, obg, Ag, Cgh);
  pair_kernel<<<dim3(Bn * 72), dim3(256), 0, stream>>>(obg, Ag, Cgh, W2, b2, wtg, Q, cand);
  rankmask_kernel<<<dim3(Bn * 8), dim3(256), 0, stream>>>(O, W1, b1, W2, cand, mask);
}

// Round 17
// 53.213 us; speedup vs baseline: 2.6708x; 1.0708x over previous
//
#include <hip/hip_runtime.h>
#include <math.h>

#define Bn 16
#define Nn 256
#define Mm (Nn*(Nn-1)/2)   /* 32640 */
#define CHUNK 4080         /* Mm / 8 */

typedef __attribute__((ext_vector_type(8))) _Float16 f16x8;
typedef __attribute__((ext_vector_type(4))) _Float16 f16x4;
typedef __attribute__((ext_vector_type(4))) float f32x4;
typedef __attribute__((ext_vector_type(16))) float f32x16;

typedef union { f16x8 v; _Float16 h[8]; unsigned u[4]; } H8;
typedef union { f16x4 v; _Float16 h[4]; } H4;

#define MFMA(acc, a, b) \
  acc = __builtin_amdgcn_mfma_f32_16x16x32_f16((a), (b), (acc), 0, 0, 0)
#define MFMA32(acc, a, b) \
  acc = __builtin_amdgcn_mfma_f32_32x32x16_f16((a), (b), (acc), 0, 0, 0)

__device__ __forceinline__ void top2_update(float v, int m,
    float& v1, int& i1, float& v2, int& i2)
{
  bool c1 = (v > v1) || (v == v1 && m < i1);
  bool c2 = (v > v2) || (v == v2 && m < i2);
  float nv2 = c1 ? v1 : (c2 ? v : v2);
  int   ni2 = c1 ? i1 : (c2 ? m : i2);
  v1 = c1 ? v : v1;  i1 = c1 ? m : i1;
  v2 = nv2;          i2 = ni2;
}

// permuted h-index for 32x32 C/D layout: h = (r&3)+8*(r>>2)+4*hi+32*X
// stored at px = X*32 + hi*16 + r
__device__ __forceinline__ int hperm(int h) {
  return (h >> 5) * 32 + ((h >> 2) & 1) * 16 + (h & 3) + 4 * ((h & 31) >> 3);
}

// ---------------------------------------------------------------------------
// Fused prep (128 blocks): blocks 0..63 transpose W1 -> wtg fp16 [h][k];
// blocks 64..127: obg = fp16(O); A = O@W1a + b1 (f32, h-PERMUTED for the
// 32x32 C/D layout); C = O@W1b (fp16, h-PERMUTED).
// ---------------------------------------------------------------------------
__global__ __launch_bounds__(256) void prep_all(
    const float* __restrict__ O, const float* __restrict__ W1,
    const float* __restrict__ b1,
    _Float16* __restrict__ wtg, _Float16* __restrict__ obg,
    float* __restrict__ Ag, _Float16* __restrict__ Cgh)
{
  const int t = threadIdx.x;
  if (blockIdx.x < 64) {
    const int h = blockIdx.x;
    wtg[h * 256 + t] = (_Float16)W1[t * 64 + h];
    return;
  }

  __shared__ __align__(16) _Float16 s_ob[64][72];
  __shared__ __align__(16) _Float16 s_w[64][136];   // W1a/b^T [h][k<128]
  const int l = t & 63, wv = t >> 6;
  const int lo = l & 15, g = l >> 4;
  const int bb = blockIdx.x - 64;
  const int b = bb >> 2, rt = bb & 3;
  const int r0 = rt * 64;
  const float* Ob = O + ((size_t)b * Nn + r0) * 64;

  #pragma unroll
  for (int p = 0; p < 4; ++p) {
    int v = t + p * 256;
    int r = v >> 4, c4 = (v & 15) * 4;
    float4 x = ((const float4*)Ob)[v];
    H4 pk; pk.h[0] = (_Float16)x.x; pk.h[1] = (_Float16)x.y;
           pk.h[2] = (_Float16)x.z; pk.h[3] = (_Float16)x.w;
    *(f16x4*)&s_ob[r][c4] = pk.v;
    *(f16x4*)&obg[((size_t)b * Nn + r0 + r) * 64 + c4] = pk.v;
  }
  #pragma unroll
  for (int p = 0; p < 32; ++p) {
    int kk = p * 4 + (t >> 6), h = t & 63;
    s_w[h][kk] = (_Float16)W1[kk * 64 + h];
  }
  __syncthreads();

  H8 aop[2];
  #pragma unroll
  for (int ks = 0; ks < 2; ++ks)
    aop[ks].v = *(const f16x8*)&s_ob[wv * 16 + lo][ks * 32 + g * 8];

  #pragma unroll
  for (int half = 0; half < 2; ++half) {
    #pragma unroll
    for (int nf = 0; nf < 4; ++nf) {
      f32x4 ac = {0.f, 0.f, 0.f, 0.f};
      #pragma unroll
      for (int ks = 0; ks < 2; ++ks) {
        H8 bop; bop.v = *(const f16x8*)&s_w[nf * 16 + lo][half * 64 + ks * 32 + g * 8];
        MFMA(ac, aop[ks].v, bop.v);
      }
      const int h  = nf * 16 + lo;
      const int px = hperm(h);
      if (half == 0) {
        float bbv = b1[h];
        #pragma unroll
        for (int r = 0; r < 4; ++r)
          Ag[((size_t)b * Nn + r0 + wv * 16 + g * 4 + r) * 64 + px] = ac[r] + bbv;
      } else {
        #pragma unroll
        for (int r = 0; r < 4; ++r)
          Cgh[((size_t)b * Nn + r0 + wv * 16 + g * 4 + r) * 64 + px] = (_Float16)ac[r];
      }
    }
  }
}

// ---------------------------------------------------------------------------
// Pair kernel (32x32x16 MFMA): one block = (batch, 16x32 tile), 4 waves.
// Wave owns 4 i-rows; ONE iteration per i-row covers all 32 j-cols x 64 h:
// 2 acc chains (h 0..31 / 32..63, f32x16) x 8 K-steps = 16 MFMA.
// 4 iterations/wave (was 8), 1 shfl/iter (was 2). A/C/W2 pre-permuted so
// acc-init and EPI are contiguous b128 reads. Q stores 128B coalesced.
// Tripwire: WRITE_SIZE >> 2 MB = cap-forced spill.
// ---------------------------------------------------------------------------
__global__ __launch_bounds__(256, 2) void pair_kernel(
    const _Float16* __restrict__ obg,
    const float* __restrict__ Ag,
    const _Float16* __restrict__ Cgh,
    const float* __restrict__ W2,
    const float* __restrict__ b2,
    const _Float16* __restrict__ wtg,
    float* __restrict__ Q,
    float* __restrict__ cand)
{
  __shared__ __align__(16) _Float16 s_wt[64][136];  // pairwise W^T [h][k-128]
  __shared__ __align__(16) _Float16 s_oi[16][72];
  __shared__ __align__(16) float s_Ap[16][68];      // A rows, h-permuted
  __shared__ float s_w2p[64];                       // W2, h-permuted
  __shared__ float s_red[4][4];

  const int t  = threadIdx.x;
  const int l  = t & 63, wv = t >> 6;
  const int lo32 = l & 31, hi = l >> 5;

  const int blk    = blockIdx.x;
  const int within = blk >> 3;                    // 0..143
  const int batch  = (blk & 7) * 2 + within / 72; // XCD (blk%8) -> batches 2x,2x+1
  int tl           = within % 72;
  int a = 0;
  while (tl >= 8 - (a >> 1)) { tl -= 8 - (a >> 1); ++a; }
  const int c   = (a >> 1) + tl;
  const int ti0 = a * 16, tj0 = c * 32;
  const bool isdiag = (tj0 < ti0 + 16);

  const size_t obase = (size_t)batch * Nn;
  const size_t qbase = (size_t)batch * Mm;

  // ---- stage s_wt + s_oi + s_Ap + s_w2p ----
  {
    const int h = t >> 2, kq = (t & 3) * 32;
    #pragma unroll
    for (int q = 0; q < 4; ++q)
      *(f16x8*)&s_wt[h][kq + q * 8] =
          *(const f16x8*)&wtg[h * 256 + 128 + kq + q * 8];
  }
  {
    int r = t >> 4, c4 = (t & 15) * 4;
    *(f16x4*)&s_oi[r][c4] =
        *(const f16x4*)&obg[(obase + ti0 + r) * 64 + c4];
    *(f32x4*)&s_Ap[r][c4] =
        *(const f32x4*)&Ag[(obase + ti0 + r) * 64 + c4];
    if (t < 64) s_w2p[hperm(t)] = W2[t];
  }
  __syncthreads();

  // ---- hoists ----
  // W fragments: chain A rows = lo32 (h 0..31), chain B rows = 32+lo32.
  // step s8: k = s8*16 + hi*8 + e (e=0..7)
  H8 wA[8], wB[8];
  #pragma unroll
  for (int s8 = 0; s8 < 8; ++s8) {
    wA[s8].v = *(const f16x8*)&s_wt[     lo32][s8 * 16 + hi * 8];
    wB[s8].v = *(const f16x8*)&s_wt[32 + lo32][s8 * 16 + hi * 8];
  }
  // oj row for this lane's pair column
  const int j = tj0 + lo32;
  H8 ojb[4];
  #pragma unroll
  for (int s4 = 0; s4 < 4; ++s4)
    ojb[s4].v = *(const f16x8*)&obg[(obase + j) * 64 + s4 * 16 + hi * 8];
  // C terms (permuted layout -> contiguous)
  f32x4 cinA[4], cinB[4];
  #pragma unroll
  for (int q = 0; q < 4; ++q) {
    H4 ca; ca.v = *(const f16x4*)&Cgh[(obase + j) * 64 + hi * 16 + q * 4];
    H4 cb; cb.v = *(const f16x4*)&Cgh[(obase + j) * 64 + 32 + hi * 16 + q * 4];
    #pragma unroll
    for (int e = 0; e < 4; ++e) {
      cinA[q][e] = (float)ca.h[e];
      cinB[q][e] = (float)cb.h[e];
    }
  }

  const float b2v = b2[0];
  float v1 = -INFINITY, v2 = -INFINITY;
  int   i1 = 0x7fffffff, i2 = 0x7fffffff;

  // ---- main loop: 4 iterations (one per i-row) ----
  #pragma unroll
  for (int ii = 0; ii < 4; ++ii) {
    const int iL = wv * 4 + ii;
    const int i  = ti0 + iL;

    // oi row (broadcast)
    H8 oib[4];
    #pragma unroll
    for (int s4 = 0; s4 < 4; ++s4)
      oib[s4].v = *(const f16x8*)&s_oi[iL][s4 * 16 + hi * 8];

    // acc init = A terms (permuted, broadcast b128)
    f32x16 accA, accB;
    #pragma unroll
    for (int q = 0; q < 4; ++q) {
      f32x4 av = *(const f32x4*)&s_Ap[iL][hi * 16 + q * 4];
      f32x4 bv = *(const f32x4*)&s_Ap[iL][32 + hi * 16 + q * 4];
      #pragma unroll
      for (int e = 0; e < 4; ++e) {
        accA[q * 4 + e] = av[e];
        accB[q * 4 + e] = bv[e];
      }
    }

    __builtin_amdgcn_s_setprio(1);
    #pragma unroll
    for (int s4 = 0; s4 < 4; ++s4) {
      H8 fd, fp;
      fd.v = oib[s4].v - ojb[s4].v;
      #pragma unroll
      for (int q = 0; q < 4; ++q) fd.u[q] &= 0x7FFF7FFFu;
      fp.v = oib[s4].v * ojb[s4].v;
      MFMA32(accA, wA[s4].v,     fd.v);
      MFMA32(accB, wB[s4].v,     fd.v);
      MFMA32(accA, wA[s4 + 4].v, fp.v);
      MFMA32(accB, wB[s4 + 4].v, fp.v);
    }
    __builtin_amdgcn_s_setprio(0);

    // epilogue: +C, relu, W2 dot (all per-register), 1 shfl
    float pA = 0.f, pB = 0.f;
    #pragma unroll
    for (int q = 0; q < 4; ++q) {
      f32x4 wa = *(const f32x4*)&s_w2p[hi * 16 + q * 4];
      f32x4 wb = *(const f32x4*)&s_w2p[32 + hi * 16 + q * 4];
      #pragma unroll
      for (int e = 0; e < 4; ++e) {
        pA = fmaf(fmaxf(accA[q * 4 + e] + cinA[q][e], 0.f), wa[e], pA);
        pB = fmaf(fmaxf(accB[q * 4 + e] + cinB[q][e], 0.f), wb[e], pB);
      }
    }
    float part = pA + pB;
    part += __shfl_xor(part, 32);

    if (l < 32 && (!isdiag || j > i)) {
      const int mb = i * (Nn - 1) - (i * (i - 1)) / 2 - i - 1;
      const float qv = part + b2v;
      Q[qbase + mb + j] = qv;
      top2_update(qv, mb + j, v1, i1, v2, i2);
    }
  }

  // ---- wave + block top-2 reduce -> cand ----
  #pragma unroll
  for (int s = 1; s < 64; s <<= 1) {
    float u1 = __shfl_xor(v1, s); int j1 = __shfl_xor(i1, s);
    float u2 = __shfl_xor(v2, s); int j2 = __shfl_xor(i2, s);
    top2_update(u1, j1, v1, i1, v2, i2);
    top2_update(u2, j2, v1, i1, v2, i2);
  }
  if (l == 0) {
    s_red[wv][0] = v1; s_red[wv][1] = __int_as_float(i1);
    s_red[wv][2] = v2; s_red[wv][3] = __int_as_float(i2);
  }
  __syncthreads();
  if (t == 0) {
    float a1 = s_red[0][0]; int x1 = __float_as_int(s_red[0][1]);
    float a2 = s_red[0][2]; int x2 = __float_as_int(s_red[0][3]);
    #pragma unroll
    for (int e = 1; e < 4; ++e) {
      top2_update(s_red[e][0], __float_as_int(s_red[e][1]), a1, x1, a2, x2);
      top2_update(s_red[e][2], __float_as_int(s_red[e][3]), a1, x1, a2, x2);
    }
    float* cp = cand + ((size_t)batch * 72 + within % 72) * 4;
    cp[0] = a1; cp[1] = __int_as_float(x1);
    cp[2] = a2; cp[3] = __int_as_float(x2);
  }
}

// ---------------------------------------------------------------------------
// Rank+mask kernel: grid (B x 8). Merges 144 candidates -> top-8,
// recomputes those 8 exactly in fp32 (wave-per-candidate, h-per-lane),
// picks exact top-2 (jax tie rule), writes mask slice.
// ---------------------------------------------------------------------------
__global__ __launch_bounds__(256) void rankmask_kernel(
    const float* __restrict__ O, const float* __restrict__ W1,
    const float* __restrict__ b1, const float* __restrict__ W2,
    const float* __restrict__ cand, float* __restrict__ mask)
{
  const int b   = blockIdx.x >> 3;
  const int cch = blockIdx.x & 7;
  const int t   = threadIdx.x;
  const int wv  = t >> 6, h = t & 63;
  __shared__ float s_cv[144];
  __shared__ int   s_ci[144];
  __shared__ int   s_m[8];
  __shared__ int   s_ij[8][2];
  __shared__ float s_or[8][2][64];
  __shared__ float s_qe[8];
  __shared__ int   s_k0, s_k1;

  if (t < 144) {
    const float* cp = cand + (size_t)(b * 72 + (t >> 1)) * 4;
    s_cv[t] = cp[(t & 1) * 2];
    s_ci[t] = __float_as_int(cp[(t & 1) * 2 + 1]);
  }
  __syncthreads();
  if (t < 144) {
    float v = s_cv[t]; int m = s_ci[t];
    int rank = 0;
    for (int e = 0; e < 144; ++e) {
      float u = s_cv[e]; int n = s_ci[e];
      rank += (u > v || (u == v && n < m)) ? 1 : 0;
    }
    if (rank < 8) s_m[rank] = m;
  }
  __syncthreads();
  if (t < 16) {
    int m = s_m[t >> 1];
    int i = 0, rem = m;
    while (rem >= Nn - 1 - i) { rem -= Nn - 1 - i; ++i; }
    int j = i + 1 + rem;
    s_ij[t >> 1][t & 1] = (t & 1) ? j : i;
  }
  __syncthreads();
  {
    int cc = t >> 5, rr = (t >> 4) & 1, c4 = (t & 15) * 4;
    int row = s_ij[cc][rr];
    *(float4*)&s_or[cc][rr][c4] = *(const float4*)&O[((size_t)b * Nn + row) * 64 + c4];
  }
  __syncthreads();
  #pragma unroll
  for (int p = 0; p < 2; ++p) {
    const int cc = p * 4 + wv;
    float z = b1[h];
    #pragma unroll 8
    for (int d = 0; d < 64; ++d) {
      float oi = s_or[cc][0][d], oj = s_or[cc][1][d];
      float f3 = fabsf(oi - oj), f4 = oi * oj;
      z += oi * W1[d * 64 + h] + oj * W1[(64 + d) * 64 + h]
         + f3 * W1[(128 + d) * 64 + h] + f4 * W1[(192 + d) * 64 + h];
    }
    float part = fmaxf(z, 0.f) * W2[h];
    #pragma unroll
    for (int s = 1; s < 64; s <<= 1) part += __shfl_xor(part, s);
    if (h == 0) s_qe[cc] = part;
  }
  __syncthreads();
  if (t == 0) {
    float v1 = -INFINITY, v2 = -INFINITY;
    int   i1 = 0x7fffffff, i2 = 0x7fffffff;
    for (int e = 0; e < 8; ++e)
      top2_update(s_qe[e], s_m[e], v1, i1, v2, i2);
    s_k0 = i1; s_k1 = i2;
  }
  __syncthreads();

  const int k0 = s_k0, k1 = s_k1;
  float* mb = mask + (size_t)b * Mm;
  const int m0 = cch * CHUNK;
  for (int m = m0 + t; m < m0 + CHUNK; m += 256)
    mb[m] = (m == k0 || m == k1) ? 1.0f : 0.0f;
}

extern "C" void kernel_launch(void* const* d_in, const int* in_sizes, int n_in,
                              void* d_out, int out_size, void* d_ws, size_t ws_size,
                              hipStream_t stream) {
  const float* O  = (const float*)d_in[0];
  const float* W1 = (const float*)d_in[1];
  const float* b1 = (const float*)d_in[2];
  const float* W2 = (const float*)d_in[3];
  const float* b2 = (const float*)d_in[4];

  float* Q    = (float*)d_out;
  float* mask = Q + (size_t)Bn * Mm;

  char* ws = (char*)d_ws;
  _Float16* wtg = (_Float16*)ws;                               // 32768 B
  _Float16* obg = (_Float16*)(ws + 32768);                     // 524288 B
  float*    Ag  = (float*)(ws + 32768 + 524288);               // 1048576 B
  _Float16* Cgh = (_Float16*)(ws + 32768 + 524288 + 1048576);  // 524288 B
  float*    cand = (float*)(ws + 32768 + 524288 + 1048576 + 524288); // 18432 B

  prep_all<<<dim3(128), dim3(256), 0, stream>>>(O, W1, b1, wtg, obg, Ag, Cgh);
  pair_kernel<<<dim3(Bn * 72), dim3(256), 0, stream>>>(obg, Ag, Cgh, W2, b2, wtg, Q, cand);
  rankmask_kernel<<<dim3(Bn * 8), dim3(256), 0, stream>>>(O, W1, b1, W2, cand, mask);
}